// Round 6
// baseline (203.121 us; speedup 1.0000x reference)
//
#include <hip/hip_runtime.h>
#include <hip/hip_bf16.h>
#include <math.h>

#define Bb   16
#define HWn  4096
#define Ff   512
#define Kk   32
#define ROWS 64            // rows per tile
#define GCH  32            // chunks per b (128 rows per block)

typedef __attribute__((ext_vector_type(8))) short  short8;
typedef __attribute__((ext_vector_type(4))) float  f32x4;

// ws layout (float offsets) — small stuff only
#define WS_SSUM  0                          // 512
#define WS_EOUT  512
#define WS_ATTN  (WS_EOUT + Bb * Ff)
#define WS_CWB   (WS_ATTN + Bb * Ff)        // 8192 float slots (16384 bf16)
#define WS_C2    (WS_CWB + 8192)
#define WS_SM    (WS_C2 + 32)

// d_out scratch (float offsets into 33.5M featuremap region)
#define SCR_PART 0                          // 512 blocks * 16384 = 8,388,608
#define SCR_RED  16777216                   // +262,144

static __device__ __forceinline__ unsigned int pack2bf(float a, float b) {
    union { __hip_bfloat162 h; unsigned int u; } p;
    p.h = __float22bfloat162_rn(make_float2(a, b));
    return p.u;
}

// ---------------------------------------------------------------------------
// prep: cw -> bf16; fold c2[k]*sm[k]*log2e and sm[k]*log2e. 1 block, 256 thr.
// ---------------------------------------------------------------------------
__global__ void prep(const float* __restrict__ cw, const float* __restrict__ smth,
                     unsigned short* __restrict__ cwb,
                     float* __restrict__ c2l2, float* __restrict__ sml2)
{
    const int t = threadIdx.x;
    const float4* c4 = (const float4*)cw;
    #pragma unroll
    for (int j = 0; j < 16; ++j) {
        const int i = t + j * 256;
        const float4 v = c4[i];
        *reinterpret_cast<uint2*>(&cwb[i * 4]) =
            make_uint2(pack2bf(v.x, v.y), pack2bf(v.z, v.w));
    }
    const int k = t >> 3, sk = t & 7;
    float p = 0.f;
    #pragma unroll
    for (int j = 0; j < 16; ++j) {
        const float4 v = c4[k * 128 + sk + j * 8];
        p = fmaf(v.x, v.x, fmaf(v.y, v.y, fmaf(v.z, v.z, fmaf(v.w, v.w, p))));
    }
    p += __shfl_xor(p, 1); p += __shfl_xor(p, 2); p += __shfl_xor(p, 4);
    if (sk == 0) {
        const float L2E = 1.4426950408889634f;
        const float sm = smth[k];
        sml2[k] = sm * L2E;
        c2l2[k] = p * sm * L2E;
    }
}

// ---------------------------------------------------------------------------
// enc_pass v6: grid (32, 16), block 512 (8 waves). 128 rows/block, 2 tiles of 64.
//  stage : fp32 global -> bf16 row-major fb16 (v4-proven chunk-XOR swizzle) + x2
//  phase1: MFMA xc over 8-wave quadrants (kh = wave>>2, nh = wave&3) -> lgx LDS
//  softmax: 512-thread wave-parallel (8 lanes/row); lgx buffer reused for sN
//  phase2: v2/v3-proven VALU rank-update; wave owns 4 k, lane owns f=lane*8..+7
//  writeback: one 32x512 fp32 partial per block (plain stores) + tiny s_sum atomics
// ---------------------------------------------------------------------------
__global__ __launch_bounds__(512, 4) void enc_pass(
    const float* __restrict__ x, const unsigned short* __restrict__ cwb,
    const float* __restrict__ c2l2, const float* __restrict__ sml2,
    float* __restrict__ part, float* __restrict__ s_sum)
{
    __shared__ __align__(16) unsigned short fb16[ROWS * 512]; // 64 KB
    __shared__ float scratch[2304];   // lgx [32][65] then sN [64][36]
    __shared__ float x2s[ROWS];
    __shared__ float sm_s[32], c2_s[32];
    __shared__ float swred[8][32];

    const int tid  = threadIdx.x;
    const int wave = tid >> 6, lane = tid & 63;
    const int col  = lane & 15, g = lane >> 4;
    const int b    = blockIdx.y;
    const int cx   = blockIdx.x;

    if (tid < 32) { sm_s[tid] = sml2[tid]; c2_s[tid] = c2l2[tid]; }

    const int srow = tid >> 3;       // 0..63 (staging/softmax row)
    const int sf   = tid & 7;        // f-octant / k-quad slice

    float acc[4][8];
    #pragma unroll
    for (int j = 0; j < 4; ++j)
        #pragma unroll
        for (int i = 0; i < 8; ++i) acc[j][i] = 0.f;
    float ssl[4] = {0.f, 0.f, 0.f, 0.f};

    const float4* xb4 = (const float4*)(x + ((size_t)b * HWn + cx * 128) * Ff);

    for (int t = 0; t < 2; ++t) {
        if (t) __syncthreads();                    // fb16/scratch reuse guard
        // ---- stage: global fp32 -> bf16 LDS (swizzled) + fp32 x2 ----
        {
            float p = 0.f;
            #pragma unroll
            for (int j = 0; j < 16; ++j) {
                const int f4n = sf + j * 8;        // 0..127
                const float4 v = xb4[(t * ROWS + srow) * 128 + f4n];
                p = fmaf(v.x, v.x, fmaf(v.y, v.y, fmaf(v.z, v.z, fmaf(v.w, v.w, p))));
                const int idx = srow * 512 +
                    ((((f4n >> 1) ^ (srow & 7)) << 3) | ((f4n & 1) << 2));
                *reinterpret_cast<uint2*>(&fb16[idx]) =
                    make_uint2(pack2bf(v.x, v.y), pack2bf(v.z, v.w));
            }
            p += __shfl_xor(p, 1); p += __shfl_xor(p, 2); p += __shfl_xor(p, 4);
            if (sf == 0) x2s[srow] = p;
        }
        __syncthreads();
        // ---- phase 1: 8-wave quadrant MFMA xc[k][n] -> lgx ----
        {
            const int kh = wave >> 2, nh = wave & 3;
            const int nl = nh * 16 + col;
            f32x4 c0 = {0.f, 0.f, 0.f, 0.f};
            const unsigned short* arow = cwb + (kh * 16 + col) * 512 + g * 8;
            const int nswz = (nl & 7) << 3;
            #pragma unroll
            for (int fs = 0; fs < 16; ++fs) {
                const short8 a0 = *(const short8*)(arow + fs * 32);
                const short8 bf = *(const short8*)&fb16[nl * 512 + ((((fs * 4 + g) << 3)) ^ nswz)];
                c0 = __builtin_amdgcn_mfma_f32_16x16x32_bf16(a0, bf, c0, 0, 0, 0);
            }
            #pragma unroll
            for (int r = 0; r < 4; ++r)
                scratch[(kh * 16 + g * 4 + r) * 65 + nl] = c0[r];   // lgx[k][n]
        }
        __syncthreads();
        // ---- softmax (row srow, k = sf*4..+3): read lgx -> regs ----
        float lg[4];
        {
            const float x2v = x2s[srow];
            #pragma unroll
            for (int r = 0; r < 4; ++r) {
                const int k = sf * 4 + r;
                lg[r] = fmaf(sm_s[k], fmaf(-2.f, scratch[k * 65 + srow], x2v), c2_s[k]);
            }
        }
        __syncthreads();                           // scratch role switch lgx -> sN
        {
            float m = fmaxf(fmaxf(lg[0], lg[1]), fmaxf(lg[2], lg[3]));
            m = fmaxf(m, __shfl_xor(m, 1));
            m = fmaxf(m, __shfl_xor(m, 2));
            m = fmaxf(m, __shfl_xor(m, 4));
            float e[4], sum = 0.f;
            #pragma unroll
            for (int r = 0; r < 4; ++r) { e[r] = exp2f(lg[r] - m); sum += e[r]; }
            sum += __shfl_xor(sum, 1); sum += __shfl_xor(sum, 2); sum += __shfl_xor(sum, 4);
            const float inv = 1.f / sum;
            #pragma unroll
            for (int r = 0; r < 4; ++r) {
                const float s = e[r] * inv;
                scratch[srow * 36 + sf * 4 + r] = s;    // sN[n][k]
                ssl[r] += s;
            }
        }
        __syncthreads();
        // ---- phase 2: VALU rank-64 update; wave owns k=wave*4..+3, lane f=lane*8 ----
        {
            const int kq = wave * 4;
            #pragma unroll 4
            for (int n = 0; n < ROWS; ++n) {
                const f32x4 sv = *(const f32x4*)&scratch[n * 36 + kq];
                const uint4 u = *(const uint4*)&fb16[n * 512 + ((lane ^ (n & 7)) << 3)];
                float fx[8];
                fx[0] = __uint_as_float(u.x << 16);
                fx[1] = __uint_as_float(u.x & 0xffff0000u);
                fx[2] = __uint_as_float(u.y << 16);
                fx[3] = __uint_as_float(u.y & 0xffff0000u);
                fx[4] = __uint_as_float(u.z << 16);
                fx[5] = __uint_as_float(u.z & 0xffff0000u);
                fx[6] = __uint_as_float(u.w << 16);
                fx[7] = __uint_as_float(u.w & 0xffff0000u);
                #pragma unroll
                for (int j = 0; j < 4; ++j) {
                    const float sj = sv[j];
                    #pragma unroll
                    for (int i = 0; i < 8; ++i)
                        acc[j][i] = fmaf(sj, fx[i], acc[j][i]);
                }
            }
        }
    }
    // ---- s_sum block reduce: rows within wave (lane bits 3..5), then LDS ----
    __syncthreads();                               // scratch free; also phase-2 done
    #pragma unroll
    for (int r = 0; r < 4; ++r) {
        float v = ssl[r];
        v += __shfl_xor(v, 8); v += __shfl_xor(v, 16); v += __shfl_xor(v, 32);
        if (lane < 8) swred[wave][lane * 4 + r] = v;
    }
    __syncthreads();
    if (tid < 32) {
        float a = 0.f;
        #pragma unroll
        for (int w = 0; w < 8; ++w) a += swred[w][tid];
        atomicAdd(&s_sum[b * Kk + tid], a);
    }
    // ---- partial writeback: [chunk][k][f] fp32, plain stores ----
    {
        float* basep = part + (size_t)(b * GCH + cx) * (Kk * Ff) +
                       (size_t)(wave * 4) * Ff + lane * 8;
        #pragma unroll
        for (int j = 0; j < 4; ++j) {
            *reinterpret_cast<float4*>(basep + j * Ff) =
                make_float4(acc[j][0], acc[j][1], acc[j][2], acc[j][3]);
            *reinterpret_cast<float4*>(basep + j * Ff + 4) =
                make_float4(acc[j][4], acc[j][5], acc[j][6], acc[j][7]);
        }
    }
}

// ---------------------------------------------------------------------------
// enc_red: sum 32 per-chunk partials -> enc[b][k][f]. grid 1024 x 256.
// ---------------------------------------------------------------------------
__global__ void enc_red(const float* __restrict__ scr, float* __restrict__ outp)
{
    const int idx = blockIdx.x * 256 + threadIdx.x;    // 0 .. 262143
    const int b   = idx >> 14;
    const int rem = idx & 16383;
    const float* p = scr + (size_t)b * GCH * 16384 + rem;
    float a = 0.f;
    #pragma unroll
    for (int c = 0; c < GCH; ++c) a += p[c * 16384];
    outp[idx] = a;
}

// ---------------------------------------------------------------------------
// enc_finish: enc = enc_red - s_sum*cw; BN + ReLU; sum over k; se_loss.
// ---------------------------------------------------------------------------
__global__ void enc_finish(const float* __restrict__ enc_acc,
                           const float* __restrict__ s_sum,
                           const float* __restrict__ cw,
                           const float* __restrict__ gamma,
                           const float* __restrict__ beta,
                           const float* __restrict__ mean,
                           const float* __restrict__ var,
                           const float* __restrict__ se_w,
                           const float* __restrict__ se_b,
                           float* __restrict__ enc_out,
                           float* __restrict__ se_out)
{
    __shared__ float ss[Kk];
    __shared__ float red[8];
    const int b = blockIdx.x, f = threadIdx.x;
    if (f < Kk) ss[f] = s_sum[b * Kk + f];
    __syncthreads();
    const float m  = mean[f];
    const float g  = gamma[f];
    const float bt = beta[f];
    const float iv = rsqrtf(var[f] + 1e-3f);
    float a = 0.f;
    #pragma unroll 4
    for (int k = 0; k < Kk; ++k) {
        float v = enc_acc[((long)b * Kk + k) * Ff + f] - ss[k] * cw[k * Ff + f];
        v = (v - m) * iv * g + bt;
        a += fmaxf(v, 0.f);
    }
    enc_out[b * Ff + f] = a;
    float p = a * se_w[f];
    p += __shfl_down(p, 32); p += __shfl_down(p, 16); p += __shfl_down(p, 8);
    p += __shfl_down(p, 4);  p += __shfl_down(p, 2);  p += __shfl_down(p, 1);
    if ((f & 63) == 0) red[f >> 6] = p;
    __syncthreads();
    if (f == 0) {
        float t = 0.f;
        #pragma unroll
        for (int i = 0; i < 8; ++i) t += red[i];
        se_out[b] = t + se_b[0];
    }
}

// ---------------------------------------------------------------------------
// attn_fc: grid 8 blocks x 512; W column-block read exactly once.
// ---------------------------------------------------------------------------
__global__ void attn_fc(const float* __restrict__ enc_out,
                        const float* __restrict__ W,
                        const float* __restrict__ bias,
                        float* __restrict__ attn)
{
    __shared__ float eo[Bb][Ff];
    const int t = threadIdx.x, fg = blockIdx.x;
    #pragma unroll
    for (int j = 0; j < 4; ++j)
        reinterpret_cast<float4*>(&eo[0][0])[t + j * 512] =
            reinterpret_cast<const float4*>(enc_out)[t + j * 512];
    __syncthreads();
    const int f  = fg * 64 + (t & 63);
    const int b0 = t >> 6;
    float a0 = bias[f], a1 = bias[f];
    #pragma unroll 8
    for (int fp = 0; fp < Ff; ++fp) {
        const float w = W[fp * Ff + f];
        a0 = fmaf(eo[b0][fp],     w, a0);
        a1 = fmaf(eo[b0 + 8][fp], w, a1);
    }
    attn[b0 * Ff + f]       = 1.f / (1.f + expf(-a0));
    attn[(b0 + 8) * Ff + f] = 1.f / (1.f + expf(-a1));
}

// ---------------------------------------------------------------------------
// bcast_mul: featuremaps = attn (broadcast over H,W) * inputs
// ---------------------------------------------------------------------------
__global__ void bcast_mul(const float4* __restrict__ x4,
                          const float* __restrict__ attn,
                          float4* __restrict__ o4)
{
    const int stride = gridDim.x * blockDim.x;
    const int total4 = Bb * HWn * Ff / 4;
    for (int i = blockIdx.x * blockDim.x + threadIdx.x; i < total4; i += stride) {
        const float4 v = x4[i];
        const int f4 = i & 127;
        const int bb = i >> 19;
        const float4 a = *reinterpret_cast<const float4*>(&attn[bb * Ff + f4 * 4]);
        o4[i] = make_float4(v.x * a.x, v.y * a.y, v.z * a.z, v.w * a.w);
    }
}

extern "C" void kernel_launch(void* const* d_in, const int* in_sizes, int n_in,
                              void* d_out, int out_size, void* d_ws, size_t ws_size,
                              hipStream_t stream)
{
    (void)in_sizes; (void)n_in; (void)out_size; (void)ws_size;
    const float* x     = (const float*)d_in[0];
    const float* cw    = (const float*)d_in[1];
    const float* smth  = (const float*)d_in[2];
    const float* gamma = (const float*)d_in[3];
    const float* beta  = (const float*)d_in[4];
    const float* mean  = (const float*)d_in[5];
    const float* var   = (const float*)d_in[6];
    const float* Wenc  = (const float*)d_in[7];
    const float* benc  = (const float*)d_in[8];
    const float* Wse   = (const float*)d_in[9];
    const float* bse   = (const float*)d_in[10];

    float* out = (float*)d_out;
    float* ws  = (float*)d_ws;
    float* ssum = ws + WS_SSUM;
    float* eout = ws + WS_EOUT;
    float* attn = ws + WS_ATTN;
    unsigned short* cwb = (unsigned short*)(ws + WS_CWB);
    float* c2l2 = ws + WS_C2;
    float* sml2 = ws + WS_SM;

    float* scr_part = out + SCR_PART;
    float* scr_red  = out + SCR_RED;

    hipMemsetAsync(ssum, 0, (size_t)Bb * Kk * sizeof(float), stream);
    prep<<<1, 256, 0, stream>>>(cw, smth, cwb, c2l2, sml2);
    enc_pass<<<dim3(GCH, Bb), 512, 0, stream>>>(x, cwb, c2l2, sml2, scr_part, ssum);
    enc_red<<<1024, 256, 0, stream>>>(scr_part, scr_red);
    enc_finish<<<Bb, 512, 0, stream>>>(scr_red, ssum, cw, gamma, beta, mean, var,
                                       Wse, bse, eout, out + (long)Bb * HWn * Ff);
    attn_fc<<<8, 512, 0, stream>>>(eout, Wenc, benc, attn);
    bcast_mul<<<2048, 256, 0, stream>>>((const float4*)x, attn, (float4*)out);
}

// Round 7
// 184.168 us; speedup vs baseline: 1.1029x; 1.1029x over previous
//
#include <hip/hip_runtime.h>
#include <hip/hip_bf16.h>
#include <math.h>

#define Bb   16
#define HWn  4096
#define Ff   512
#define Kk   32
#define ROWS 64            // rows per tile
#define GCH  32            // chunks per b (128 rows per block)

typedef __attribute__((ext_vector_type(8))) short  short8;
typedef __attribute__((ext_vector_type(4))) float  f32x4;

// ws layout (float offsets) — small stuff only
#define WS_SSUM  0                          // 512
#define WS_EOUT  512
#define WS_ATTN  (WS_EOUT + Bb * Ff)
#define WS_CWB   (WS_ATTN + Bb * Ff)        // 8192 float slots (16384 bf16)
#define WS_C2    (WS_CWB + 8192)
#define WS_SM    (WS_C2 + 32)

// d_out scratch (float offsets into 33.5M featuremap region)
#define SCR_PART 0                          // 512 blocks * 16384 = 8,388,608
#define SCR_RED  16777216                   // +262,144

static __device__ __forceinline__ unsigned int pack2bf(float a, float b) {
    union { __hip_bfloat162 h; unsigned int u; } p;
    p.h = __float22bfloat162_rn(make_float2(a, b));
    return p.u;
}

// ---------------------------------------------------------------------------
// prep: cw -> bf16; fold c2[k]*sm[k]*log2e and sm[k]*log2e. 1 block, 256 thr.
// ---------------------------------------------------------------------------
__global__ void prep(const float* __restrict__ cw, const float* __restrict__ smth,
                     unsigned short* __restrict__ cwb,
                     float* __restrict__ c2l2, float* __restrict__ sml2)
{
    const int t = threadIdx.x;
    const float4* c4 = (const float4*)cw;
    #pragma unroll
    for (int j = 0; j < 16; ++j) {
        const int i = t + j * 256;
        const float4 v = c4[i];
        *reinterpret_cast<uint2*>(&cwb[i * 4]) =
            make_uint2(pack2bf(v.x, v.y), pack2bf(v.z, v.w));
    }
    const int k = t >> 3, sk = t & 7;
    float p = 0.f;
    #pragma unroll
    for (int j = 0; j < 16; ++j) {
        const float4 v = c4[k * 128 + sk + j * 8];
        p = fmaf(v.x, v.x, fmaf(v.y, v.y, fmaf(v.z, v.z, fmaf(v.w, v.w, p))));
    }
    p += __shfl_xor(p, 1); p += __shfl_xor(p, 2); p += __shfl_xor(p, 4);
    if (sk == 0) {
        const float L2E = 1.4426950408889634f;
        const float sm = smth[k];
        sml2[k] = sm * L2E;
        c2l2[k] = p * sm * L2E;
    }
}

// ---------------------------------------------------------------------------
// enc_pass v7 = v6 structure + {launch_bounds fix, half-tile reg prefetch,
// b128 stage writes, x2-in-register}.
// grid (32, 16), block 512 (8 waves). 128 rows/block, 2 tiles of 64.
// ---------------------------------------------------------------------------
__global__ __launch_bounds__(512, 2) void enc_pass(
    const float* __restrict__ x, const unsigned short* __restrict__ cwb,
    const float* __restrict__ c2l2, const float* __restrict__ sml2,
    float* __restrict__ part, float* __restrict__ s_sum)
{
    __shared__ __align__(16) unsigned short fb16[ROWS * 512]; // 64 KB
    __shared__ float scratch[2304];   // lgx [32][65] then sN [64][36]
    __shared__ float sm_s[32], c2_s[32];
    __shared__ float swred[8][32];

    const int tid  = threadIdx.x;
    const int wave = tid >> 6, lane = tid & 63;
    const int col  = lane & 15, g = lane >> 4;
    const int b    = blockIdx.y;
    const int cx   = blockIdx.x;

    if (tid < 32) { sm_s[tid] = sml2[tid]; c2_s[tid] = c2l2[tid]; }

    const int srow = tid >> 3;       // 0..63 (staging/softmax row)
    const int sf   = tid & 7;        // f-octant / k-quad slice

    float acc[4][8];
    #pragma unroll
    for (int j = 0; j < 4; ++j)
        #pragma unroll
        for (int i = 0; i < 8; ++i) acc[j][i] = 0.f;
    float ssl[4] = {0.f, 0.f, 0.f, 0.f};

    const float4* xb4  = (const float4*)(x + ((size_t)b * HWn + cx * 128) * Ff);
    const float4* rowp = xb4 + srow * 128;

    // prologue: halfA of tile 0 (pairs c = sf + p*8, p=0..3)
    float4 pA[8];
    #pragma unroll
    for (int p = 0; p < 4; ++p) {
        pA[2 * p]     = rowp[2 * sf + p * 16];
        pA[2 * p + 1] = rowp[2 * sf + p * 16 + 1];
    }

    for (int t = 0; t < 2; ++t) {
        if (t) __syncthreads();                    // fb16/scratch reuse guard
        const float4* trow = rowp + t * ROWS * 128;
        float x2v;
        // ---- stage: halfA (prefetched) + halfB (JIT); b128 writes; x2 in regs
        {
            float px = 0.f;
            #pragma unroll
            for (int p = 0; p < 4; ++p) {
                const float4 a = pA[2 * p], c4v = pA[2 * p + 1];
                px = fmaf(a.x, a.x, fmaf(a.y, a.y, fmaf(a.z, a.z, fmaf(a.w, a.w, px))));
                px = fmaf(c4v.x, c4v.x, fmaf(c4v.y, c4v.y, fmaf(c4v.z, c4v.z, fmaf(c4v.w, c4v.w, px))));
                const int c   = sf + p * 8;
                const int idx = srow * 512 + ((c ^ (srow & 7)) << 3);
                *reinterpret_cast<uint4*>(&fb16[idx]) =
                    make_uint4(pack2bf(a.x, a.y), pack2bf(a.z, a.w),
                               pack2bf(c4v.x, c4v.y), pack2bf(c4v.z, c4v.w));
            }
            // JIT halfB loads
            float4 qB[8];
            #pragma unroll
            for (int p = 0; p < 4; ++p) {
                qB[2 * p]     = trow[2 * sf + (p + 4) * 16];
                qB[2 * p + 1] = trow[2 * sf + (p + 4) * 16 + 1];
            }
            // prefetch next tile's halfA (flies across phase1+softmax+phase2)
            if (t == 0) {
                #pragma unroll
                for (int p = 0; p < 4; ++p) {
                    pA[2 * p]     = rowp[ROWS * 128 + 2 * sf + p * 16];
                    pA[2 * p + 1] = rowp[ROWS * 128 + 2 * sf + p * 16 + 1];
                }
            }
            #pragma unroll
            for (int p = 0; p < 4; ++p) {
                const float4 a = qB[2 * p], c4v = qB[2 * p + 1];
                px = fmaf(a.x, a.x, fmaf(a.y, a.y, fmaf(a.z, a.z, fmaf(a.w, a.w, px))));
                px = fmaf(c4v.x, c4v.x, fmaf(c4v.y, c4v.y, fmaf(c4v.z, c4v.z, fmaf(c4v.w, c4v.w, px))));
                const int c   = sf + (p + 4) * 8;
                const int idx = srow * 512 + ((c ^ (srow & 7)) << 3);
                *reinterpret_cast<uint4*>(&fb16[idx]) =
                    make_uint4(pack2bf(a.x, a.y), pack2bf(a.z, a.w),
                               pack2bf(c4v.x, c4v.y), pack2bf(c4v.z, c4v.w));
            }
            px += __shfl_xor(px, 1); px += __shfl_xor(px, 2); px += __shfl_xor(px, 4);
            x2v = px;                                  // all 8 threads/row hold it
        }
        __syncthreads();
        // ---- phase 1: 8-wave quadrant MFMA xc[k][n] -> lgx (v6 proven) ----
        {
            const int kh = wave >> 2, nh = wave & 3;
            const int nl = nh * 16 + col;
            f32x4 c0 = {0.f, 0.f, 0.f, 0.f};
            const unsigned short* arow = cwb + (kh * 16 + col) * 512 + g * 8;
            const int nswz = (nl & 7) << 3;
            #pragma unroll
            for (int fs = 0; fs < 16; ++fs) {
                const short8 a0 = *(const short8*)(arow + fs * 32);
                const short8 bf = *(const short8*)&fb16[nl * 512 + ((((fs * 4 + g) << 3)) ^ nswz)];
                c0 = __builtin_amdgcn_mfma_f32_16x16x32_bf16(a0, bf, c0, 0, 0, 0);
            }
            #pragma unroll
            for (int r = 0; r < 4; ++r)
                scratch[(kh * 16 + g * 4 + r) * 65 + nl] = c0[r];   // lgx[k][n]
        }
        __syncthreads();
        // ---- softmax (row srow, k = sf*4..+3), x2 from register ----
        float lg[4];
        {
            #pragma unroll
            for (int r = 0; r < 4; ++r) {
                const int k = sf * 4 + r;
                lg[r] = fmaf(sm_s[k], fmaf(-2.f, scratch[k * 65 + srow], x2v), c2_s[k]);
            }
        }
        __syncthreads();                           // scratch role switch lgx -> sN
        {
            float m = fmaxf(fmaxf(lg[0], lg[1]), fmaxf(lg[2], lg[3]));
            m = fmaxf(m, __shfl_xor(m, 1));
            m = fmaxf(m, __shfl_xor(m, 2));
            m = fmaxf(m, __shfl_xor(m, 4));
            float e[4], sum = 0.f;
            #pragma unroll
            for (int r = 0; r < 4; ++r) { e[r] = exp2f(lg[r] - m); sum += e[r]; }
            sum += __shfl_xor(sum, 1); sum += __shfl_xor(sum, 2); sum += __shfl_xor(sum, 4);
            const float inv = 1.f / sum;
            #pragma unroll
            for (int r = 0; r < 4; ++r) {
                const float s = e[r] * inv;
                scratch[srow * 36 + sf * 4 + r] = s;    // sN[n][k]
                ssl[r] += s;
            }
        }
        __syncthreads();
        // ---- phase 2: VALU rank-64; wave owns k=wave*4..+3, lane f=lane*8 ----
        {
            const int kq = wave * 4;
            #pragma unroll 4
            for (int n = 0; n < ROWS; ++n) {
                const f32x4 sv = *(const f32x4*)&scratch[n * 36 + kq];
                const uint4 u = *(const uint4*)&fb16[n * 512 + ((lane ^ (n & 7)) << 3)];
                float fx[8];
                fx[0] = __uint_as_float(u.x << 16);
                fx[1] = __uint_as_float(u.x & 0xffff0000u);
                fx[2] = __uint_as_float(u.y << 16);
                fx[3] = __uint_as_float(u.y & 0xffff0000u);
                fx[4] = __uint_as_float(u.z << 16);
                fx[5] = __uint_as_float(u.z & 0xffff0000u);
                fx[6] = __uint_as_float(u.w << 16);
                fx[7] = __uint_as_float(u.w & 0xffff0000u);
                #pragma unroll
                for (int j = 0; j < 4; ++j) {
                    const float sj = sv[j];
                    #pragma unroll
                    for (int i = 0; i < 8; ++i)
                        acc[j][i] = fmaf(sj, fx[i], acc[j][i]);
                }
            }
        }
    }
    // ---- s_sum block reduce ----
    __syncthreads();
    #pragma unroll
    for (int r = 0; r < 4; ++r) {
        float v = ssl[r];
        v += __shfl_xor(v, 8); v += __shfl_xor(v, 16); v += __shfl_xor(v, 32);
        if (lane < 8) swred[wave][lane * 4 + r] = v;
    }
    __syncthreads();
    if (tid < 32) {
        float a = 0.f;
        #pragma unroll
        for (int w = 0; w < 8; ++w) a += swred[w][tid];
        atomicAdd(&s_sum[b * Kk + tid], a);
    }
    // ---- partial writeback: [chunk][k][f] fp32, coalesced float4 ----
    {
        float* basep = part + (size_t)(b * GCH + cx) * (Kk * Ff) +
                       (size_t)(wave * 4) * Ff + lane * 8;
        #pragma unroll
        for (int j = 0; j < 4; ++j) {
            *reinterpret_cast<float4*>(basep + j * Ff) =
                make_float4(acc[j][0], acc[j][1], acc[j][2], acc[j][3]);
            *reinterpret_cast<float4*>(basep + j * Ff + 4) =
                make_float4(acc[j][4], acc[j][5], acc[j][6], acc[j][7]);
        }
    }
}

// ---------------------------------------------------------------------------
// enc_red: sum 32 per-chunk partials -> enc[b][k][f]. grid 1024 x 256.
// ---------------------------------------------------------------------------
__global__ void enc_red(const float* __restrict__ scr, float* __restrict__ outp)
{
    const int idx = blockIdx.x * 256 + threadIdx.x;    // 0 .. 262143
    const int b   = idx >> 14;
    const int rem = idx & 16383;
    const float* p = scr + (size_t)b * GCH * 16384 + rem;
    float a = 0.f;
    #pragma unroll
    for (int c = 0; c < GCH; ++c) a += p[c * 16384];
    outp[idx] = a;
}

// ---------------------------------------------------------------------------
// enc_finish: enc = enc_red - s_sum*cw; BN + ReLU; sum over k; se_loss.
// ---------------------------------------------------------------------------
__global__ void enc_finish(const float* __restrict__ enc_acc,
                           const float* __restrict__ s_sum,
                           const float* __restrict__ cw,
                           const float* __restrict__ gamma,
                           const float* __restrict__ beta,
                           const float* __restrict__ mean,
                           const float* __restrict__ var,
                           const float* __restrict__ se_w,
                           const float* __restrict__ se_b,
                           float* __restrict__ enc_out,
                           float* __restrict__ se_out)
{
    __shared__ float ss[Kk];
    __shared__ float red[8];
    const int b = blockIdx.x, f = threadIdx.x;
    if (f < Kk) ss[f] = s_sum[b * Kk + f];
    __syncthreads();
    const float m  = mean[f];
    const float g  = gamma[f];
    const float bt = beta[f];
    const float iv = rsqrtf(var[f] + 1e-3f);
    float a = 0.f;
    #pragma unroll 4
    for (int k = 0; k < Kk; ++k) {
        float v = enc_acc[((long)b * Kk + k) * Ff + f] - ss[k] * cw[k * Ff + f];
        v = (v - m) * iv * g + bt;
        a += fmaxf(v, 0.f);
    }
    enc_out[b * Ff + f] = a;
    float p = a * se_w[f];
    p += __shfl_down(p, 32); p += __shfl_down(p, 16); p += __shfl_down(p, 8);
    p += __shfl_down(p, 4);  p += __shfl_down(p, 2);  p += __shfl_down(p, 1);
    if ((f & 63) == 0) red[f >> 6] = p;
    __syncthreads();
    if (f == 0) {
        float t = 0.f;
        #pragma unroll
        for (int i = 0; i < 8; ++i) t += red[i];
        se_out[b] = t + se_b[0];
    }
}

// ---------------------------------------------------------------------------
// attn_fc: grid 8 blocks x 512; W column-block read exactly once.
// ---------------------------------------------------------------------------
__global__ void attn_fc(const float* __restrict__ enc_out,
                        const float* __restrict__ W,
                        const float* __restrict__ bias,
                        float* __restrict__ attn)
{
    __shared__ float eo[Bb][Ff];
    const int t = threadIdx.x, fg = blockIdx.x;
    #pragma unroll
    for (int j = 0; j < 4; ++j)
        reinterpret_cast<float4*>(&eo[0][0])[t + j * 512] =
            reinterpret_cast<const float4*>(enc_out)[t + j * 512];
    __syncthreads();
    const int f  = fg * 64 + (t & 63);
    const int b0 = t >> 6;
    float a0 = bias[f], a1 = bias[f];
    #pragma unroll 8
    for (int fp = 0; fp < Ff; ++fp) {
        const float w = W[fp * Ff + f];
        a0 = fmaf(eo[b0][fp],     w, a0);
        a1 = fmaf(eo[b0 + 8][fp], w, a1);
    }
    attn[b0 * Ff + f]       = 1.f / (1.f + expf(-a0));
    attn[(b0 + 8) * Ff + f] = 1.f / (1.f + expf(-a1));
}

// ---------------------------------------------------------------------------
// bcast_mul: featuremaps = attn (broadcast over H,W) * inputs
// ---------------------------------------------------------------------------
__global__ void bcast_mul(const float4* __restrict__ x4,
                          const float* __restrict__ attn,
                          float4* __restrict__ o4)
{
    const int stride = gridDim.x * blockDim.x;
    const int total4 = Bb * HWn * Ff / 4;
    for (int i = blockIdx.x * blockDim.x + threadIdx.x; i < total4; i += stride) {
        const float4 v = x4[i];
        const int f4 = i & 127;
        const int bb = i >> 19;
        const float4 a = *reinterpret_cast<const float4*>(&attn[bb * Ff + f4 * 4]);
        o4[i] = make_float4(v.x * a.x, v.y * a.y, v.z * a.z, v.w * a.w);
    }
}

extern "C" void kernel_launch(void* const* d_in, const int* in_sizes, int n_in,
                              void* d_out, int out_size, void* d_ws, size_t ws_size,
                              hipStream_t stream)
{
    (void)in_sizes; (void)n_in; (void)out_size; (void)ws_size;
    const float* x     = (const float*)d_in[0];
    const float* cw    = (const float*)d_in[1];
    const float* smth  = (const float*)d_in[2];
    const float* gamma = (const float*)d_in[3];
    const float* beta  = (const float*)d_in[4];
    const float* mean  = (const float*)d_in[5];
    const float* var   = (const float*)d_in[6];
    const float* Wenc  = (const float*)d_in[7];
    const float* benc  = (const float*)d_in[8];
    const float* Wse   = (const float*)d_in[9];
    const float* bse   = (const float*)d_in[10];

    float* out = (float*)d_out;
    float* ws  = (float*)d_ws;
    float* ssum = ws + WS_SSUM;
    float* eout = ws + WS_EOUT;
    float* attn = ws + WS_ATTN;
    unsigned short* cwb = (unsigned short*)(ws + WS_CWB);
    float* c2l2 = ws + WS_C2;
    float* sml2 = ws + WS_SM;

    float* scr_part = out + SCR_PART;
    float* scr_red  = out + SCR_RED;

    hipMemsetAsync(ssum, 0, (size_t)Bb * Kk * sizeof(float), stream);
    prep<<<1, 256, 0, stream>>>(cw, smth, cwb, c2l2, sml2);
    enc_pass<<<dim3(GCH, Bb), 512, 0, stream>>>(x, cwb, c2l2, sml2, scr_part, ssum);
    enc_red<<<1024, 256, 0, stream>>>(scr_part, scr_red);
    enc_finish<<<Bb, 512, 0, stream>>>(scr_red, ssum, cw, gamma, beta, mean, var,
                                       Wse, bse, eout, out + (long)Bb * HWn * Ff);
    attn_fc<<<8, 512, 0, stream>>>(eout, Wenc, benc, attn);
    bcast_mul<<<2048, 256, 0, stream>>>((const float4*)x, attn, (float4*)out);
}

// Round 8
// 179.835 us; speedup vs baseline: 1.1295x; 1.0241x over previous
//
#include <hip/hip_runtime.h>
#include <hip/hip_bf16.h>
#include <math.h>

#define Bb   16
#define HWn  4096
#define Ff   512
#define Kk   32
#define GCH  32            // n-chunks per b (128 rows per chunk)

typedef __attribute__((ext_vector_type(8))) short  short8;
typedef __attribute__((ext_vector_type(4))) float  f32x4;

// ws layout (float offsets) — small stuff only
#define WS_SSUM  0                          // 512
#define WS_EOUT  512
#define WS_ATTN  (WS_EOUT + Bb * Ff)
#define WS_CWB   (WS_ATTN + Bb * Ff)        // 8192 float slots (16384 bf16)
#define WS_C2    (WS_CWB + 8192)
#define WS_SM    (WS_C2 + 32)

// d_out scratch (float offsets into 33.5M featuremap region)
#define SCR_PART 0                          // 512 * 16384 = 8,388,608
#define SCR_S    10000000                   // 2,097,152 bf16 = 1,048,576 float slots
#define SCR_RED  16777216                   // +262,144

static __device__ __forceinline__ unsigned int pack2bf(float a, float b) {
    union { __hip_bfloat162 h; unsigned int u; } p;
    p.h = __float22bfloat162_rn(make_float2(a, b));
    return p.u;
}

// ---------------------------------------------------------------------------
// prep: cw -> bf16; fold c2[k]*sm[k]*log2e and sm[k]*log2e. 1 block, 256 thr.
// ---------------------------------------------------------------------------
__global__ void prep(const float* __restrict__ cw, const float* __restrict__ smth,
                     unsigned short* __restrict__ cwb,
                     float* __restrict__ c2l2, float* __restrict__ sml2)
{
    const int t = threadIdx.x;
    const float4* c4 = (const float4*)cw;
    #pragma unroll
    for (int j = 0; j < 16; ++j) {
        const int i = t + j * 256;
        const float4 v = c4[i];
        *reinterpret_cast<uint2*>(&cwb[i * 4]) =
            make_uint2(pack2bf(v.x, v.y), pack2bf(v.z, v.w));
    }
    const int k = t >> 3, sk = t & 7;
    float p = 0.f;
    #pragma unroll
    for (int j = 0; j < 16; ++j) {
        const float4 v = c4[k * 128 + sk + j * 8];
        p = fmaf(v.x, v.x, fmaf(v.y, v.y, fmaf(v.z, v.z, fmaf(v.w, v.w, p))));
    }
    p += __shfl_xor(p, 1); p += __shfl_xor(p, 2); p += __shfl_xor(p, 4);
    if (sk == 0) {
        const float L2E = 1.4426950408889634f;
        const float sm = smth[k];
        sml2[k] = sm * L2E;
        c2l2[k] = p * sm * L2E;
    }
}

// ---------------------------------------------------------------------------
// softmax_pass: grid (32, 16), block 512 (8 waves). Wave owns 16 rows,
// fully independent: B-frags straight from global fp32, A = cwb (L2-hot),
// in-register softmax (v2-proven layout), s -> bf16 [n][k] global,
// s_sum via per-wave shfl reduce + one block reduce.
// ---------------------------------------------------------------------------
__global__ __launch_bounds__(512, 2) void softmax_pass(
    const float* __restrict__ x, const unsigned short* __restrict__ cwb,
    const float* __restrict__ c2l2, const float* __restrict__ sml2,
    unsigned short* __restrict__ s_out, float* __restrict__ s_sum)
{
    __shared__ float sm_s[32], c2_s[32];
    __shared__ float swred[8][32];

    const int tid  = threadIdx.x;
    const int wave = tid >> 6, lane = tid & 63;
    const int col  = lane & 15, g = lane >> 4;
    const int b    = blockIdx.y;
    const int n    = blockIdx.x * 128 + wave * 16 + col;   // this lane's row

    if (tid < 32) { sm_s[tid] = sml2[tid]; c2_s[tid] = c2l2[tid]; }
    __syncthreads();

    // ---- logits via MFMA, x read directly from global ----
    const float4* xr = (const float4*)(x + ((size_t)b * HWn + n) * Ff) + g * 2;
    const unsigned short* a0p = cwb + col * 512 + g * 8;
    const unsigned short* a1p = a0p + 16 * 512;
    f32x4 c0 = {0.f, 0.f, 0.f, 0.f}, c1 = {0.f, 0.f, 0.f, 0.f};
    float px = 0.f;
    #pragma unroll
    for (int fs = 0; fs < 16; ++fs) {
        const float4 v0 = xr[fs * 8];
        const float4 v1 = xr[fs * 8 + 1];
        px = fmaf(v0.x, v0.x, fmaf(v0.y, v0.y, fmaf(v0.z, v0.z, fmaf(v0.w, v0.w, px))));
        px = fmaf(v1.x, v1.x, fmaf(v1.y, v1.y, fmaf(v1.z, v1.z, fmaf(v1.w, v1.w, px))));
        union { uint4 u; short8 s; } bu;
        bu.u = make_uint4(pack2bf(v0.x, v0.y), pack2bf(v0.z, v0.w),
                          pack2bf(v1.x, v1.y), pack2bf(v1.z, v1.w));
        const short8 a0 = *(const short8*)(a0p + fs * 32);
        const short8 a1 = *(const short8*)(a1p + fs * 32);
        c0 = __builtin_amdgcn_mfma_f32_16x16x32_bf16(a0, bu.s, c0, 0, 0, 0);
        c1 = __builtin_amdgcn_mfma_f32_16x16x32_bf16(a1, bu.s, c1, 0, 0, 0);
    }
    px += __shfl_xor(px, 16); px += __shfl_xor(px, 32);    // full-row ||x||^2

    // ---- softmax over k=32 (lane holds 8 k's for row n) ----
    float lg[8];
    #pragma unroll
    for (int r = 0; r < 4; ++r) {
        const int k0 = g * 4 + r;
        lg[r]     = fmaf(sm_s[k0],      fmaf(-2.f, c0[r], px), c2_s[k0]);
        lg[4 + r] = fmaf(sm_s[k0 + 16], fmaf(-2.f, c1[r], px), c2_s[k0 + 16]);
    }
    float m = lg[0];
    #pragma unroll
    for (int j = 1; j < 8; ++j) m = fmaxf(m, lg[j]);
    m = fmaxf(m, __shfl_xor(m, 16)); m = fmaxf(m, __shfl_xor(m, 32));
    float e[8], sum = 0.f;
    #pragma unroll
    for (int j = 0; j < 8; ++j) { e[j] = exp2f(lg[j] - m); sum += e[j]; }
    sum += __shfl_xor(sum, 16); sum += __shfl_xor(sum, 32);
    const float inv = 1.f / sum;
    #pragma unroll
    for (int j = 0; j < 8; ++j) e[j] *= inv;

    // ---- write s (bf16, [n][k]) ----
    {
        unsigned short* sp = s_out + ((size_t)b * HWn + n) * 32 + g * 4;
        *reinterpret_cast<uint2*>(sp)      = make_uint2(pack2bf(e[0], e[1]), pack2bf(e[2], e[3]));
        *reinterpret_cast<uint2*>(sp + 16) = make_uint2(pack2bf(e[4], e[5]), pack2bf(e[6], e[7]));
    }
    // ---- s_sum: reduce over the wave's 16 rows (col bits = lane bits 0..3) ----
    #pragma unroll
    for (int j = 0; j < 8; ++j) {
        float v = e[j];
        v += __shfl_xor(v, 1); v += __shfl_xor(v, 2);
        v += __shfl_xor(v, 4); v += __shfl_xor(v, 8);
        if (col == 0) swred[wave][((j & 4) << 2) + g * 4 + (j & 3)] = v;
    }
    __syncthreads();
    if (tid < 32) {
        float a = 0.f;
        #pragma unroll
        for (int w = 0; w < 8; ++w) a += swred[w][tid];
        atomicAdd(&s_sum[b * Kk + tid], a);
    }
}

// ---------------------------------------------------------------------------
// enc_gemm: grid (32, 16), block 512 (8 waves). Chunk = 128 rows.
// Stage s-tile (bf16 -> fp32 LDS, 16 KB), one barrier, then pure streaming:
// per n: broadcast LDS b128 (wave's 4 k) + 2 coalesced float4 x loads + 32 FMA.
// Writes one 32x512 fp32 partial per block.
// ---------------------------------------------------------------------------
__global__ __launch_bounds__(512, 2) void enc_gemm(
    const float* __restrict__ x, const unsigned short* __restrict__ s_in,
    float* __restrict__ part)
{
    __shared__ __align__(16) float s_lds[128 * 32];    // 16 KB
    const int tid  = threadIdx.x;
    const int wave = tid >> 6, lane = tid & 63;
    const int b    = blockIdx.y, cx = blockIdx.x;
    const int n0   = cx * 128;

    // stage s: 4096 bf16, one uint4 (8 bf16) per thread -> fp32 LDS
    {
        const uint4 v = reinterpret_cast<const uint4*>(
            s_in + ((size_t)b * HWn + n0) * 32)[tid];
        float* d = &s_lds[tid * 8];
        d[0] = __uint_as_float(v.x << 16);
        d[1] = __uint_as_float(v.x & 0xffff0000u);
        d[2] = __uint_as_float(v.y << 16);
        d[3] = __uint_as_float(v.y & 0xffff0000u);
        d[4] = __uint_as_float(v.z << 16);
        d[5] = __uint_as_float(v.z & 0xffff0000u);
        d[6] = __uint_as_float(v.w << 16);
        d[7] = __uint_as_float(v.w & 0xffff0000u);
    }
    __syncthreads();

    float acc[4][8];
    #pragma unroll
    for (int j = 0; j < 4; ++j)
        #pragma unroll
        for (int i = 0; i < 8; ++i) acc[j][i] = 0.f;

    const int kq = wave * 4;
    const float4* xp = (const float4*)(x + ((size_t)b * HWn + n0) * Ff) + lane * 2;
    #pragma unroll 4
    for (int nn = 0; nn < 128; ++nn) {
        const f32x4 sv = *(const f32x4*)&s_lds[nn * 32 + kq];   // broadcast
        const float4 v0 = xp[nn * 128];
        const float4 v1 = xp[nn * 128 + 1];
        const float fx[8] = {v0.x, v0.y, v0.z, v0.w, v1.x, v1.y, v1.z, v1.w};
        #pragma unroll
        for (int j = 0; j < 4; ++j) {
            const float sj = sv[j];
            #pragma unroll
            for (int i = 0; i < 8; ++i)
                acc[j][i] = fmaf(sj, fx[i], acc[j][i]);
        }
    }
    // partial writeback: [chunk][k][f] fp32, coalesced float4
    float* basep = part + (size_t)(b * GCH + cx) * (Kk * Ff) +
                   (size_t)(wave * 4) * Ff + lane * 8;
    #pragma unroll
    for (int j = 0; j < 4; ++j) {
        *reinterpret_cast<float4*>(basep + j * Ff) =
            make_float4(acc[j][0], acc[j][1], acc[j][2], acc[j][3]);
        *reinterpret_cast<float4*>(basep + j * Ff + 4) =
            make_float4(acc[j][4], acc[j][5], acc[j][6], acc[j][7]);
    }
}

// ---------------------------------------------------------------------------
// enc_red: sum 32 per-chunk partials -> enc[b][k][f]. grid 1024 x 256.
// ---------------------------------------------------------------------------
__global__ void enc_red(const float* __restrict__ scr, float* __restrict__ outp)
{
    const int idx = blockIdx.x * 256 + threadIdx.x;    // 0 .. 262143
    const int b   = idx >> 14;
    const int rem = idx & 16383;
    const float* p = scr + (size_t)b * GCH * 16384 + rem;
    float a = 0.f;
    #pragma unroll
    for (int c = 0; c < GCH; ++c) a += p[c * 16384];
    outp[idx] = a;
}

// ---------------------------------------------------------------------------
// enc_finish: enc = enc_red - s_sum*cw; BN + ReLU; sum over k; se_loss.
// ---------------------------------------------------------------------------
__global__ void enc_finish(const float* __restrict__ enc_acc,
                           const float* __restrict__ s_sum,
                           const float* __restrict__ cw,
                           const float* __restrict__ gamma,
                           const float* __restrict__ beta,
                           const float* __restrict__ mean,
                           const float* __restrict__ var,
                           const float* __restrict__ se_w,
                           const float* __restrict__ se_b,
                           float* __restrict__ enc_out,
                           float* __restrict__ se_out)
{
    __shared__ float ss[Kk];
    __shared__ float red[8];
    const int b = blockIdx.x, f = threadIdx.x;
    if (f < Kk) ss[f] = s_sum[b * Kk + f];
    __syncthreads();
    const float m  = mean[f];
    const float g  = gamma[f];
    const float bt = beta[f];
    const float iv = rsqrtf(var[f] + 1e-3f);
    float a = 0.f;
    #pragma unroll 4
    for (int k = 0; k < Kk; ++k) {
        float v = enc_acc[((long)b * Kk + k) * Ff + f] - ss[k] * cw[k * Ff + f];
        v = (v - m) * iv * g + bt;
        a += fmaxf(v, 0.f);
    }
    enc_out[b * Ff + f] = a;
    float p = a * se_w[f];
    p += __shfl_down(p, 32); p += __shfl_down(p, 16); p += __shfl_down(p, 8);
    p += __shfl_down(p, 4);  p += __shfl_down(p, 2);  p += __shfl_down(p, 1);
    if ((f & 63) == 0) red[f >> 6] = p;
    __syncthreads();
    if (f == 0) {
        float t = 0.f;
        #pragma unroll
        for (int i = 0; i < 8; ++i) t += red[i];
        se_out[b] = t + se_b[0];
    }
}

// ---------------------------------------------------------------------------
// attn_fc: grid 8 blocks x 512; W column-block read exactly once.
// ---------------------------------------------------------------------------
__global__ void attn_fc(const float* __restrict__ enc_out,
                        const float* __restrict__ W,
                        const float* __restrict__ bias,
                        float* __restrict__ attn)
{
    __shared__ float eo[Bb][Ff];
    const int t = threadIdx.x, fg = blockIdx.x;
    #pragma unroll
    for (int j = 0; j < 4; ++j)
        reinterpret_cast<float4*>(&eo[0][0])[t + j * 512] =
            reinterpret_cast<const float4*>(enc_out)[t + j * 512];
    __syncthreads();
    const int f  = fg * 64 + (t & 63);
    const int b0 = t >> 6;
    float a0 = bias[f], a1 = bias[f];
    #pragma unroll 8
    for (int fp = 0; fp < Ff; ++fp) {
        const float w = W[fp * Ff + f];
        a0 = fmaf(eo[b0][fp],     w, a0);
        a1 = fmaf(eo[b0 + 8][fp], w, a1);
    }
    attn[b0 * Ff + f]       = 1.f / (1.f + expf(-a0));
    attn[(b0 + 8) * Ff + f] = 1.f / (1.f + expf(-a1));
}

// ---------------------------------------------------------------------------
// bcast_mul: featuremaps = attn (broadcast over H,W) * inputs
// ---------------------------------------------------------------------------
__global__ void bcast_mul(const float4* __restrict__ x4,
                          const float* __restrict__ attn,
                          float4* __restrict__ o4)
{
    const int stride = gridDim.x * blockDim.x;
    const int total4 = Bb * HWn * Ff / 4;
    for (int i = blockIdx.x * blockDim.x + threadIdx.x; i < total4; i += stride) {
        const float4 v = x4[i];
        const int f4 = i & 127;
        const int bb = i >> 19;
        const float4 a = *reinterpret_cast<const float4*>(&attn[bb * Ff + f4 * 4]);
        o4[i] = make_float4(v.x * a.x, v.y * a.y, v.z * a.z, v.w * a.w);
    }
}

extern "C" void kernel_launch(void* const* d_in, const int* in_sizes, int n_in,
                              void* d_out, int out_size, void* d_ws, size_t ws_size,
                              hipStream_t stream)
{
    (void)in_sizes; (void)n_in; (void)out_size; (void)ws_size;
    const float* x     = (const float*)d_in[0];
    const float* cw    = (const float*)d_in[1];
    const float* smth  = (const float*)d_in[2];
    const float* gamma = (const float*)d_in[3];
    const float* beta  = (const float*)d_in[4];
    const float* mean  = (const float*)d_in[5];
    const float* var   = (const float*)d_in[6];
    const float* Wenc  = (const float*)d_in[7];
    const float* benc  = (const float*)d_in[8];
    const float* Wse   = (const float*)d_in[9];
    const float* bse   = (const float*)d_in[10];

    float* out = (float*)d_out;
    float* ws  = (float*)d_ws;
    float* ssum = ws + WS_SSUM;
    float* eout = ws + WS_EOUT;
    float* attn = ws + WS_ATTN;
    unsigned short* cwb = (unsigned short*)(ws + WS_CWB);
    float* c2l2 = ws + WS_C2;
    float* sml2 = ws + WS_SM;

    float* scr_part = out + SCR_PART;
    unsigned short* scr_s = (unsigned short*)(out + SCR_S);
    float* scr_red  = out + SCR_RED;

    hipMemsetAsync(ssum, 0, (size_t)Bb * Kk * sizeof(float), stream);
    prep<<<1, 256, 0, stream>>>(cw, smth, cwb, c2l2, sml2);
    softmax_pass<<<dim3(GCH, Bb), 512, 0, stream>>>(x, cwb, c2l2, sml2, scr_s, ssum);
    enc_gemm<<<dim3(GCH, Bb), 512, 0, stream>>>(x, scr_s, scr_part);
    enc_red<<<1024, 256, 0, stream>>>(scr_part, scr_red);
    enc_finish<<<Bb, 512, 0, stream>>>(scr_red, ssum, cw, gamma, beta, mean, var,
                                       Wse, bse, eout, out + (long)Bb * HWn * Ff);
    attn_fc<<<8, 512, 0, stream>>>(eout, Wenc, benc, attn);
    bcast_mul<<<2048, 256, 0, stream>>>((const float4*)x, attn, (float4*)out);
}

// Round 9
// 174.995 us; speedup vs baseline: 1.1607x; 1.0277x over previous
//
#include <hip/hip_runtime.h>
#include <hip/hip_bf16.h>
#include <math.h>

#define Bb   16
#define HWn  4096
#define Ff   512
#define Kk   32
#define GCH  32            // n-chunks per b (128 rows per chunk)

typedef __attribute__((ext_vector_type(8))) short  short8;
typedef __attribute__((ext_vector_type(4))) float  f32x4;

// ws layout (float offsets) — small stuff only
#define WS_SSUM  0                          // 512
#define WS_EOUT  512
#define WS_ATTN  (WS_EOUT + Bb * Ff)
#define WS_CWB   (WS_ATTN + Bb * Ff)        // 8192 float slots (16384 bf16)
#define WS_C2    (WS_CWB + 8192)
#define WS_SM    (WS_C2 + 32)

// d_out scratch (float offsets into 33.5M featuremap region)
#define SCR_PART 0                          // 512 * 16384 = 8,388,608
#define SCR_RED  16777216                   // +262,144

static __device__ __forceinline__ unsigned int pack2bf(float a, float b) {
    union { __hip_bfloat162 h; unsigned int u; } p;
    p.h = __float22bfloat162_rn(make_float2(a, b));
    return p.u;
}

// ---------------------------------------------------------------------------
// prep: cw -> bf16; fold c2[k]*sm[k]*log2e and sm[k]*log2e. 1 block, 256 thr.
// ---------------------------------------------------------------------------
__global__ void prep(const float* __restrict__ cw, const float* __restrict__ smth,
                     unsigned short* __restrict__ cwb,
                     float* __restrict__ c2l2, float* __restrict__ sml2)
{
    const int t = threadIdx.x;
    const float4* c4 = (const float4*)cw;
    #pragma unroll
    for (int j = 0; j < 16; ++j) {
        const int i = t + j * 256;
        const float4 v = c4[i];
        *reinterpret_cast<uint2*>(&cwb[i * 4]) =
            make_uint2(pack2bf(v.x, v.y), pack2bf(v.z, v.w));
    }
    const int k = t >> 3, sk = t & 7;
    float p = 0.f;
    #pragma unroll
    for (int j = 0; j < 16; ++j) {
        const float4 v = c4[k * 128 + sk + j * 8];
        p = fmaf(v.x, v.x, fmaf(v.y, v.y, fmaf(v.z, v.z, fmaf(v.w, v.w, p))));
    }
    p += __shfl_xor(p, 1); p += __shfl_xor(p, 2); p += __shfl_xor(p, 4);
    if (sk == 0) {
        const float L2E = 1.4426950408889634f;
        const float sm = smth[k];
        sml2[k] = sm * L2E;
        c2l2[k] = p * sm * L2E;
    }
}

// ---------------------------------------------------------------------------
// enc_fused: grid (32, 16), block 512 (8 waves). Chunk = 128 rows.
// Phase A (barrier-free, per-wave): MFMA logits from global fp32 x (B-frags
// packed in-register), in-register softmax -> s_lds fp32 [n][k]; swred.
// ONE barrier. Phase B: streaming rank-update, s broadcast from LDS, x
// re-read from global (block-local 256 KB -> L2/L3-hot). Partials out.
// ---------------------------------------------------------------------------
__global__ __launch_bounds__(512, 2) void enc_fused(
    const float* __restrict__ x, const unsigned short* __restrict__ cwb,
    const float* __restrict__ c2l2, const float* __restrict__ sml2,
    float* __restrict__ part, float* __restrict__ s_sum)
{
    __shared__ __align__(16) float s_lds[128 * 32];    // 16 KB  [n_loc][k]
    __shared__ float sm_s[32], c2_s[32];
    __shared__ float swred[8][32];

    const int tid  = threadIdx.x;
    const int wave = tid >> 6, lane = tid & 63;
    const int col  = lane & 15, g = lane >> 4;
    const int b    = blockIdx.y, cx = blockIdx.x;
    const int n_loc = wave * 16 + col;
    const int n     = cx * 128 + n_loc;

    if (tid < 32) { sm_s[tid] = sml2[tid]; c2_s[tid] = c2l2[tid]; }
    __syncthreads();

    // ================= Phase A: logits + softmax (r8-proven) =================
    {
        const float4* xr = (const float4*)(x + ((size_t)b * HWn + n) * Ff) + g * 2;
        const unsigned short* a0p = cwb + col * 512 + g * 8;
        const unsigned short* a1p = a0p + 16 * 512;
        f32x4 c0 = {0.f, 0.f, 0.f, 0.f}, c1 = {0.f, 0.f, 0.f, 0.f};
        float px = 0.f;
        #pragma unroll
        for (int fs = 0; fs < 16; ++fs) {
            const float4 v0 = xr[fs * 8];
            const float4 v1 = xr[fs * 8 + 1];
            px = fmaf(v0.x, v0.x, fmaf(v0.y, v0.y, fmaf(v0.z, v0.z, fmaf(v0.w, v0.w, px))));
            px = fmaf(v1.x, v1.x, fmaf(v1.y, v1.y, fmaf(v1.z, v1.z, fmaf(v1.w, v1.w, px))));
            union { uint4 u; short8 s; } bu;
            bu.u = make_uint4(pack2bf(v0.x, v0.y), pack2bf(v0.z, v0.w),
                              pack2bf(v1.x, v1.y), pack2bf(v1.z, v1.w));
            const short8 a0 = *(const short8*)(a0p + fs * 32);
            const short8 a1 = *(const short8*)(a1p + fs * 32);
            c0 = __builtin_amdgcn_mfma_f32_16x16x32_bf16(a0, bu.s, c0, 0, 0, 0);
            c1 = __builtin_amdgcn_mfma_f32_16x16x32_bf16(a1, bu.s, c1, 0, 0, 0);
        }
        px += __shfl_xor(px, 16); px += __shfl_xor(px, 32);    // full-row ||x||^2

        float lg[8];
        #pragma unroll
        for (int r = 0; r < 4; ++r) {
            const int k0 = g * 4 + r;
            lg[r]     = fmaf(sm_s[k0],      fmaf(-2.f, c0[r], px), c2_s[k0]);
            lg[4 + r] = fmaf(sm_s[k0 + 16], fmaf(-2.f, c1[r], px), c2_s[k0 + 16]);
        }
        float m = lg[0];
        #pragma unroll
        for (int j = 1; j < 8; ++j) m = fmaxf(m, lg[j]);
        m = fmaxf(m, __shfl_xor(m, 16)); m = fmaxf(m, __shfl_xor(m, 32));
        float e[8], sum = 0.f;
        #pragma unroll
        for (int j = 0; j < 8; ++j) { e[j] = exp2f(lg[j] - m); sum += e[j]; }
        sum += __shfl_xor(sum, 16); sum += __shfl_xor(sum, 32);
        const float inv = 1.f / sum;
        #pragma unroll
        for (int j = 0; j < 8; ++j) e[j] *= inv;

        // s -> LDS fp32 [n_loc][k]
        #pragma unroll
        for (int r = 0; r < 4; ++r) {
            s_lds[n_loc * 32 + g * 4 + r]      = e[r];
            s_lds[n_loc * 32 + 16 + g * 4 + r] = e[4 + r];
        }
        // per-wave s_sum partial (reduce over the wave's 16 rows)
        #pragma unroll
        for (int j = 0; j < 8; ++j) {
            float v = e[j];
            v += __shfl_xor(v, 1); v += __shfl_xor(v, 2);
            v += __shfl_xor(v, 4); v += __shfl_xor(v, 8);
            if (col == 0) swred[wave][((j & 4) << 2) + g * 4 + (j & 3)] = v;
        }
    }
    __syncthreads();
    // s_sum atomic (tiny; overlaps phase B of other waves)
    if (tid < 32) {
        float a = 0.f;
        #pragma unroll
        for (int w = 0; w < 8; ++w) a += swred[w][tid];
        atomicAdd(&s_sum[b * Kk + tid], a);
    }

    // ================= Phase B: rank-update streaming (r8-proven) ============
    float acc[4][8];
    #pragma unroll
    for (int j = 0; j < 4; ++j)
        #pragma unroll
        for (int i = 0; i < 8; ++i) acc[j][i] = 0.f;

    const int kq = wave * 4;
    const float4* xp = (const float4*)(x + ((size_t)b * HWn + cx * 128) * Ff) + lane * 2;
    #pragma unroll 4
    for (int nn = 0; nn < 128; ++nn) {
        const f32x4 sv = *(const f32x4*)&s_lds[nn * 32 + kq];   // broadcast
        const float4 v0 = xp[nn * 128];
        const float4 v1 = xp[nn * 128 + 1];
        const float fx[8] = {v0.x, v0.y, v0.z, v0.w, v1.x, v1.y, v1.z, v1.w};
        #pragma unroll
        for (int j = 0; j < 4; ++j) {
            const float sj = sv[j];
            #pragma unroll
            for (int i = 0; i < 8; ++i)
                acc[j][i] = fmaf(sj, fx[i], acc[j][i]);
        }
    }
    // partial writeback: [chunk][k][f] fp32, coalesced float4
    float* basep = part + (size_t)(b * GCH + cx) * (Kk * Ff) +
                   (size_t)(wave * 4) * Ff + lane * 8;
    #pragma unroll
    for (int j = 0; j < 4; ++j) {
        *reinterpret_cast<float4*>(basep + j * Ff) =
            make_float4(acc[j][0], acc[j][1], acc[j][2], acc[j][3]);
        *reinterpret_cast<float4*>(basep + j * Ff + 4) =
            make_float4(acc[j][4], acc[j][5], acc[j][6], acc[j][7]);
    }
}

// ---------------------------------------------------------------------------
// enc_red: sum 32 per-chunk partials -> enc[b][k][f]. grid 1024 x 256.
// ---------------------------------------------------------------------------
__global__ void enc_red(const float* __restrict__ scr, float* __restrict__ outp)
{
    const int idx = blockIdx.x * 256 + threadIdx.x;    // 0 .. 262143
    const int b   = idx >> 14;
    const int rem = idx & 16383;
    const float* p = scr + (size_t)b * GCH * 16384 + rem;
    float a = 0.f;
    #pragma unroll
    for (int c = 0; c < GCH; ++c) a += p[c * 16384];
    outp[idx] = a;
}

// ---------------------------------------------------------------------------
// enc_finish: enc = enc_red - s_sum*cw; BN + ReLU; sum over k; se_loss.
// ---------------------------------------------------------------------------
__global__ void enc_finish(const float* __restrict__ enc_acc,
                           const float* __restrict__ s_sum,
                           const float* __restrict__ cw,
                           const float* __restrict__ gamma,
                           const float* __restrict__ beta,
                           const float* __restrict__ mean,
                           const float* __restrict__ var,
                           const float* __restrict__ se_w,
                           const float* __restrict__ se_b,
                           float* __restrict__ enc_out,
                           float* __restrict__ se_out)
{
    __shared__ float ss[Kk];
    __shared__ float red[8];
    const int b = blockIdx.x, f = threadIdx.x;
    if (f < Kk) ss[f] = s_sum[b * Kk + f];
    __syncthreads();
    const float m  = mean[f];
    const float g  = gamma[f];
    const float bt = beta[f];
    const float iv = rsqrtf(var[f] + 1e-3f);
    float a = 0.f;
    #pragma unroll 4
    for (int k = 0; k < Kk; ++k) {
        float v = enc_acc[((long)b * Kk + k) * Ff + f] - ss[k] * cw[k * Ff + f];
        v = (v - m) * iv * g + bt;
        a += fmaxf(v, 0.f);
    }
    enc_out[b * Ff + f] = a;
    float p = a * se_w[f];
    p += __shfl_down(p, 32); p += __shfl_down(p, 16); p += __shfl_down(p, 8);
    p += __shfl_down(p, 4);  p += __shfl_down(p, 2);  p += __shfl_down(p, 1);
    if ((f & 63) == 0) red[f >> 6] = p;
    __syncthreads();
    if (f == 0) {
        float t = 0.f;
        #pragma unroll
        for (int i = 0; i < 8; ++i) t += red[i];
        se_out[b] = t + se_b[0];
    }
}

// ---------------------------------------------------------------------------
// attn_fc: grid 8 blocks x 512; W column-block read exactly once.
// ---------------------------------------------------------------------------
__global__ void attn_fc(const float* __restrict__ enc_out,
                        const float* __restrict__ W,
                        const float* __restrict__ bias,
                        float* __restrict__ attn)
{
    __shared__ float eo[Bb][Ff];
    const int t = threadIdx.x, fg = blockIdx.x;
    #pragma unroll
    for (int j = 0; j < 4; ++j)
        reinterpret_cast<float4*>(&eo[0][0])[t + j * 512] =
            reinterpret_cast<const float4*>(enc_out)[t + j * 512];
    __syncthreads();
    const int f  = fg * 64 + (t & 63);
    const int b0 = t >> 6;
    float a0 = bias[f], a1 = bias[f];
    #pragma unroll 8
    for (int fp = 0; fp < Ff; ++fp) {
        const float w = W[fp * Ff + f];
        a0 = fmaf(eo[b0][fp],     w, a0);
        a1 = fmaf(eo[b0 + 8][fp], w, a1);
    }
    attn[b0 * Ff + f]       = 1.f / (1.f + expf(-a0));
    attn[(b0 + 8) * Ff + f] = 1.f / (1.f + expf(-a1));
}

// ---------------------------------------------------------------------------
// bcast_mul: featuremaps = attn (broadcast over H,W) * inputs
// ---------------------------------------------------------------------------
__global__ void bcast_mul(const float4* __restrict__ x4,
                          const float* __restrict__ attn,
                          float4* __restrict__ o4)
{
    const int stride = gridDim.x * blockDim.x;
    const int total4 = Bb * HWn * Ff / 4;
    for (int i = blockIdx.x * blockDim.x + threadIdx.x; i < total4; i += stride) {
        const float4 v = x4[i];
        const int f4 = i & 127;
        const int bb = i >> 19;
        const float4 a = *reinterpret_cast<const float4*>(&attn[bb * Ff + f4 * 4]);
        o4[i] = make_float4(v.x * a.x, v.y * a.y, v.z * a.z, v.w * a.w);
    }
}

extern "C" void kernel_launch(void* const* d_in, const int* in_sizes, int n_in,
                              void* d_out, int out_size, void* d_ws, size_t ws_size,
                              hipStream_t stream)
{
    (void)in_sizes; (void)n_in; (void)out_size; (void)ws_size;
    const float* x     = (const float*)d_in[0];
    const float* cw    = (const float*)d_in[1];
    const float* smth  = (const float*)d_in[2];
    const float* gamma = (const float*)d_in[3];
    const float* beta  = (const float*)d_in[4];
    const float* mean  = (const float*)d_in[5];
    const float* var   = (const float*)d_in[6];
    const float* Wenc  = (const float*)d_in[7];
    const float* benc  = (const float*)d_in[8];
    const float* Wse   = (const float*)d_in[9];
    const float* bse   = (const float*)d_in[10];

    float* out = (float*)d_out;
    float* ws  = (float*)d_ws;
    float* ssum = ws + WS_SSUM;
    float* eout = ws + WS_EOUT;
    float* attn = ws + WS_ATTN;
    unsigned short* cwb = (unsigned short*)(ws + WS_CWB);
    float* c2l2 = ws + WS_C2;
    float* sml2 = ws + WS_SM;

    float* scr_part = out + SCR_PART;
    float* scr_red  = out + SCR_RED;

    hipMemsetAsync(ssum, 0, (size_t)Bb * Kk * sizeof(float), stream);
    prep<<<1, 256, 0, stream>>>(cw, smth, cwb, c2l2, sml2);
    enc_fused<<<dim3(GCH, Bb), 512, 0, stream>>>(x, cwb, c2l2, sml2, scr_part, ssum);
    enc_red<<<1024, 256, 0, stream>>>(scr_part, scr_red);
    enc_finish<<<Bb, 512, 0, stream>>>(scr_red, ssum, cw, gamma, beta, mean, var,
                                       Wse, bse, eout, out + (long)Bb * HWn * Ff);
    attn_fc<<<8, 512, 0, stream>>>(eout, Wenc, benc, attn);
    bcast_mul<<<2048, 256, 0, stream>>>((const float4*)x, attn, (float4*)out);
}